// Round 1
// baseline (854.810 us; speedup 1.0000x reference)
//
#include <hip/hip_runtime.h>
#include <hip/hip_bf16.h>

// Problem constants
#define B_ 2
#define S_ 2048
#define H_ 16
#define HD_ 64
#define D_ 1024
#define NJ_ 257      // 2*MAX_REL+1
#define RSTRIDE_ 264 // padded row stride for R (16B aligned)

typedef __bf16 v8bf __attribute__((ext_vector_type(8)));
typedef __bf16 v4bf __attribute__((ext_vector_type(4)));
typedef float  v4f  __attribute__((ext_vector_type(4)));

static __device__ __forceinline__ v4f mfma16(v8bf a, v8bf b, v4f c) {
    return __builtin_amdgcn_mfma_f32_16x16x32_bf16(a, b, c, 0, 0, 0);
}

// ---------------------------------------------------------------------------
// Split fp32 -> bf16 hi + bf16 lo (3-term split GEMMs recover ~fp32 accuracy)
// ---------------------------------------------------------------------------
__global__ void k_split2(const float* __restrict__ src, __bf16* __restrict__ h,
                         __bf16* __restrict__ l, int n4) {
    int i = blockIdx.x * blockDim.x + threadIdx.x;
    int stride = gridDim.x * blockDim.x;
    for (; i < n4; i += stride) {
        const float4 v = ((const float4*)src)[i];
        float vv[4] = {v.x, v.y, v.z, v.w};
        v4bf hv, lv;
#pragma unroll
        for (int j = 0; j < 4; j++) {
            __bf16 hb = (__bf16)vv[j];
            hv[j] = hb;
            lv[j] = (__bf16)(vv[j] - (float)hb);
        }
        *(v4bf*)(h + 4 * (size_t)i) = hv;
        *(v4bf*)(l + 4 * (size_t)i) = lv;
    }
}

// ---------------------------------------------------------------------------
// Per-(b,q) row flag: 1 if whole mask row is nonzero (fast path skips loads)
// ---------------------------------------------------------------------------
__global__ void k_rowflag(const int* __restrict__ mask, unsigned char* __restrict__ flags) {
    const int row = blockIdx.x; // 0 .. B*S-1
    const int4* mp = (const int4*)(mask + (size_t)row * S_);
    int ok = 1;
    for (int i = threadIdx.x; i < S_ / 4; i += blockDim.x) {
        int4 m = mp[i];
        ok &= (m.x != 0) & (m.y != 0) & (m.z != 0) & (m.w != 0);
    }
    int all = __syncthreads_and(ok);
    if (threadIdx.x == 0) flags[row] = (unsigned char)(all != 0);
}

// ---------------------------------------------------------------------------
// Projection GEMM: O[m,n] = sum_k A[m,k]*W[n,k]  (A,W split hi/lo, 3-term)
// MODE 0: write hi/lo bf16 outputs (Q,K). MODE 1: plain bf16 output (V).
// Tiles 64x64, K-chunks of 64, 4 waves.
// ---------------------------------------------------------------------------
template <int MODE>
__global__ __launch_bounds__(256) void k_proj(const __bf16* __restrict__ Ah,
                                              const __bf16* __restrict__ Al,
                                              const __bf16* __restrict__ Bh,
                                              const __bf16* __restrict__ Bl,
                                              __bf16* __restrict__ Oh,
                                              __bf16* __restrict__ Ol) {
    __shared__ __bf16 sAh[64][72], sAl[64][72], sBh[64][72], sBl[64][72];
    const int n0 = blockIdx.x * 64;
    const int m0 = blockIdx.y * 64;
    const int tid = threadIdx.x, lane = tid & 63, wid = tid >> 6;
    const int fr = lane & 15, fo = (lane >> 4) * 8;
    const int srow = tid >> 2, scol = (tid & 3) * 16;
    v4f acc[4] = {};
    for (int k0 = 0; k0 < D_; k0 += 64) {
        const size_t ga = (size_t)(m0 + srow) * D_ + k0 + scol;
        const size_t gb = (size_t)(n0 + srow) * D_ + k0 + scol;
        *(v8bf*)&sAh[srow][scol]     = *(const v8bf*)(Ah + ga);
        *(v8bf*)&sAh[srow][scol + 8] = *(const v8bf*)(Ah + ga + 8);
        *(v8bf*)&sAl[srow][scol]     = *(const v8bf*)(Al + ga);
        *(v8bf*)&sAl[srow][scol + 8] = *(const v8bf*)(Al + ga + 8);
        *(v8bf*)&sBh[srow][scol]     = *(const v8bf*)(Bh + gb);
        *(v8bf*)&sBh[srow][scol + 8] = *(const v8bf*)(Bh + gb + 8);
        *(v8bf*)&sBl[srow][scol]     = *(const v8bf*)(Bl + gb);
        *(v8bf*)&sBl[srow][scol + 8] = *(const v8bf*)(Bl + gb + 8);
        __syncthreads();
#pragma unroll
        for (int ks = 0; ks < 2; ks++) {
            v8bf ah = *(const v8bf*)&sAh[wid * 16 + fr][ks * 32 + fo];
            v8bf al = *(const v8bf*)&sAl[wid * 16 + fr][ks * 32 + fo];
#pragma unroll
            for (int nt = 0; nt < 4; nt++) {
                v8bf bh = *(const v8bf*)&sBh[nt * 16 + fr][ks * 32 + fo];
                v8bf bl = *(const v8bf*)&sBl[nt * 16 + fr][ks * 32 + fo];
                acc[nt] = mfma16(ah, bh, acc[nt]);
                acc[nt] = mfma16(ah, bl, acc[nt]);
                acc[nt] = mfma16(al, bh, acc[nt]);
            }
        }
        __syncthreads();
    }
#pragma unroll
    for (int nt = 0; nt < 4; nt++) {
#pragma unroll
        for (int r = 0; r < 4; r++) {
            const int row = m0 + wid * 16 + (lane >> 4) * 4 + r;
            const int col = n0 + nt * 16 + fr;
            const size_t idx = (size_t)row * D_ + col;
            float f = acc[nt][r];
            if (MODE == 0) {
                __bf16 hb = (__bf16)f;
                Oh[idx] = hb;
                Ol[idx] = (__bf16)(f - (float)hb);
            } else {
                Oh[idx] = (__bf16)f;
            }
        }
    }
}

// ---------------------------------------------------------------------------
// Rel-bias GEMM: R[bh*S + q][j] = sum_d Q[b,q,h*64+d] * rel[j][d], j in [0,257)
// K=64 (single pass). 4 waves x 16 rows, 17 j-tiles. B-frags from global (L1/L2 hot).
// ---------------------------------------------------------------------------
__global__ __launch_bounds__(256) void k_relgemm(const __bf16* __restrict__ Qh,
                                                 const __bf16* __restrict__ Ql,
                                                 const __bf16* __restrict__ relh,
                                                 const __bf16* __restrict__ rell,
                                                 float* __restrict__ Rg) {
    const int q0 = blockIdx.x * 64;
    const int bh = blockIdx.y;
    const int b = bh >> 4, h = bh & 15;
    const int tid = threadIdx.x, lane = tid & 63, wid = tid >> 6;
    const int fr = lane & 15, fo = (lane >> 4) * 8;
    const size_t qbase = (size_t)(b * S_ + q0 + wid * 16 + fr) * D_ + h * HD_;
    v8bf qa_h[2], qa_l[2];
#pragma unroll
    for (int ks = 0; ks < 2; ks++) {
        qa_h[ks] = *(const v8bf*)(Qh + qbase + ks * 32 + fo);
        qa_l[ks] = *(const v8bf*)(Ql + qbase + ks * 32 + fo);
    }
    v4f acc[17] = {};
    int jc = 16 * 16 + fr > 256 ? 256 : 0; // (computed per tile below)
    (void)jc;
#pragma unroll
    for (int jt = 0; jt < 17; jt++) {
        int j = jt * 16 + fr;
        if (j > 256) j = 256;
        const size_t rb = (size_t)j * HD_;
#pragma unroll
        for (int ks = 0; ks < 2; ks++) {
            v8bf bh_ = *(const v8bf*)(relh + rb + ks * 32 + fo);
            v8bf bl_ = *(const v8bf*)(rell + rb + ks * 32 + fo);
            acc[jt] = mfma16(qa_h[ks], bh_, acc[jt]);
            acc[jt] = mfma16(qa_h[ks], bl_, acc[jt]);
            acc[jt] = mfma16(qa_l[ks], bh_, acc[jt]);
        }
    }
    const size_t rowbase = ((size_t)bh * S_ + q0 + wid * 16 + (lane >> 4) * 4) * RSTRIDE_;
#pragma unroll
    for (int jt = 0; jt < 17; jt++) {
        const int j = jt * 16 + fr;
        if (j <= 256) {
#pragma unroll
            for (int r = 0; r < 4; r++)
                Rg[rowbase + (size_t)r * RSTRIDE_ + j] = acc[jt][r];
        }
    }
}

// ---------------------------------------------------------------------------
// Scores kernel: raw masked scores -> attn buffer (fp32), online (m,l) stats.
// Block: 64 q-rows x all 2048 k (chunks of 64). 8 waves (4 row-groups x 2 col-groups).
// QK^T via 3-term split MFMA; bias gathered from precomputed R; mask via row flags.
// ---------------------------------------------------------------------------
__global__ __launch_bounds__(512) void k_scores(const __bf16* __restrict__ Qh,
                                                const __bf16* __restrict__ Ql,
                                                const __bf16* __restrict__ Kh,
                                                const __bf16* __restrict__ Kl,
                                                const float* __restrict__ Rg,
                                                const int* __restrict__ mask,
                                                const unsigned char* __restrict__ flags,
                                                float* __restrict__ attn,
                                                float* __restrict__ mrow,
                                                float* __restrict__ lrow) {
    __shared__ __bf16 sKh[64][72], sKl[64][72];
    __shared__ float pm[2][64], pl[2][64], mrun[64], lrun[64];
    const int q0 = blockIdx.x * 64;
    const int bh = blockIdx.y;
    const int b = bh >> 4, h = bh & 15;
    const int tid = threadIdx.x, lane = tid & 63, w = tid >> 6;
    const int wr = w >> 1, wc = w & 1;
    const int fr = lane & 15, fo = (lane >> 4) * 8;

    if (tid < 64) { mrun[tid] = -3.0e38f; lrun[tid] = 0.0f; }

    // Hoist A-fragments (Q) for this wave's 16 rows
    const size_t qbase = (size_t)(b * S_ + q0 + wr * 16 + fr) * D_ + h * HD_;
    v8bf qa_h[2], qa_l[2];
#pragma unroll
    for (int ks = 0; ks < 2; ks++) {
        qa_h[ks] = *(const v8bf*)(Qh + qbase + ks * 32 + fo);
        qa_l[ks] = *(const v8bf*)(Ql + qbase + ks * 32 + fo);
    }

    const int srow = tid >> 3, sc8 = (tid & 7) * 8;
    const int myrow = wr * 16 + (lane >> 4) * 4;

    for (int kc = 0; kc < 32; kc++) {
        const int k0 = kc * 64;
        {
            const size_t gk = (size_t)(b * S_ + k0 + srow) * D_ + h * HD_ + sc8;
            *(v8bf*)&sKh[srow][sc8] = *(const v8bf*)(Kh + gk);
            *(v8bf*)&sKl[srow][sc8] = *(const v8bf*)(Kl + gk);
        }
        __syncthreads();

        v4f acc[2] = {};
#pragma unroll
        for (int ct = 0; ct < 2; ct++) {
#pragma unroll
            for (int ks = 0; ks < 2; ks++) {
                v8bf kb_h = *(const v8bf*)&sKh[wc * 32 + ct * 16 + fr][ks * 32 + fo];
                v8bf kb_l = *(const v8bf*)&sKl[wc * 32 + ct * 16 + fr][ks * 32 + fo];
                acc[ct] = mfma16(qa_h[ks], kb_h, acc[ct]);
                acc[ct] = mfma16(qa_h[ks], kb_l, acc[ct]);
                acc[ct] = mfma16(qa_l[ks], kb_h, acc[ct]);
            }
        }

        // bias + mask + raw-score write + per-wave stats
        float sv[2][4];
#pragma unroll
        for (int r = 0; r < 4; r++) {
            const int qg = q0 + myrow + r;
            const size_t rbase = ((size_t)bh * S_ + qg) * RSTRIDE_;
            const unsigned char fl = flags[b * S_ + qg];
            const size_t abase = ((size_t)bh * S_ + qg) * S_;
            const size_t mbase = ((size_t)b * S_ + qg) * S_;
#pragma unroll
            for (int ct = 0; ct < 2; ct++) {
                const int k = k0 + wc * 32 + ct * 16 + fr;
                const int dd = k - qg;
                const int j = dd < -128 ? 0 : (dd > 128 ? 256 : dd + 128);
                float s = acc[ct][r] * 0.125f + Rg[rbase + j];
                if (!fl && mask[mbase + k] == 0) s = -1e9f;
                attn[abase + k] = s;
                sv[ct][r] = s;
            }
        }
        float M[4], L[4];
#pragma unroll
        for (int r = 0; r < 4; r++) {
            float m = fmaxf(sv[0][r], sv[1][r]);
#pragma unroll
            for (int sh = 1; sh < 16; sh <<= 1) m = fmaxf(m, __shfl_xor(m, sh));
            float e = __expf(sv[0][r] - m) + __expf(sv[1][r] - m);
#pragma unroll
            for (int sh = 1; sh < 16; sh <<= 1) e += __shfl_xor(e, sh);
            M[r] = m; L[r] = e;
        }
        if (fr == 0) {
#pragma unroll
            for (int r = 0; r < 4; r++) {
                pm[wc][myrow + r] = M[r];
                pl[wc][myrow + r] = L[r];
            }
        }
        __syncthreads();
        if (tid < 64) {
            const float m0v = pm[0][tid], m1v = pm[1][tid];
            const float M2 = fmaxf(m0v, m1v);
            const float L2 = pl[0][tid] * __expf(m0v - M2) + pl[1][tid] * __expf(m1v - M2);
            const float mo = mrun[tid];
            const float mn = fmaxf(mo, M2);
            lrun[tid] = lrun[tid] * __expf(mo - mn) + L2 * __expf(M2 - mn);
            mrun[tid] = mn;
        }
        // next iteration's post-stage __syncthreads orders merge vs. readers
    }
    if (tid < 64) {
        mrow[(size_t)bh * S_ + q0 + tid] = mrun[tid];
        lrow[(size_t)bh * S_ + q0 + tid] = lrun[tid];
    }
}

// ---------------------------------------------------------------------------
// PV + softmax finalize: read raw scores, p = exp(s-m)/l, write attn in place,
// accumulate ctx = p @ V via bf16 MFMA. Block: 64 q x 64 d, k-chunks of 64.
// ---------------------------------------------------------------------------
__global__ __launch_bounds__(512) void k_pv(const __bf16* __restrict__ Vb,
                                            const float* __restrict__ mrow,
                                            const float* __restrict__ lrow,
                                            float* __restrict__ attn,
                                            __bf16* __restrict__ ctx) {
    __shared__ __bf16 sP[64][72], sV[64][72];
    __shared__ float sm[64], sli[64];
    const int q0 = blockIdx.x * 64;
    const int bh = blockIdx.y;
    const int b = bh >> 4, h = bh & 15;
    const int tid = threadIdx.x, lane = tid & 63, w = tid >> 6;
    const int wr = w >> 1, wc = w & 1;
    const int fr = lane & 15, fo = (lane >> 4) * 8;

    if (tid < 64) {
        sm[tid] = mrow[(size_t)bh * S_ + q0 + tid];
        sli[tid] = 1.0f / lrow[(size_t)bh * S_ + q0 + tid];
    }
    __syncthreads();

    const int srow = tid >> 3, sc8 = (tid & 7) * 8;
    const float mv = sm[srow], li = sli[srow];
    v4f acc[2] = {};

    for (int kc = 0; kc < 32; kc++) {
        const int k0 = kc * 64;
        {
            float* ap = attn + ((size_t)bh * S_ + q0 + srow) * S_ + k0 + sc8;
            const float4 s0 = *(const float4*)ap;
            const float4 s1 = *(const float4*)(ap + 4);
            float p[8] = {s0.x, s0.y, s0.z, s0.w, s1.x, s1.y, s1.z, s1.w};
            v8bf pb;
#pragma unroll
            for (int i = 0; i < 8; i++) {
                const float q = __expf(p[i] - mv) * li;
                p[i] = q;
                pb[i] = (__bf16)q;
            }
            *(float4*)ap       = make_float4(p[0], p[1], p[2], p[3]);
            *(float4*)(ap + 4) = make_float4(p[4], p[5], p[6], p[7]);
            *(v8bf*)&sP[srow][sc8] = pb;
            *(v8bf*)&sV[srow][sc8] =
                *(const v8bf*)(Vb + (size_t)(b * S_ + k0 + srow) * D_ + h * HD_ + sc8);
        }
        __syncthreads();
#pragma unroll
        for (int ks = 0; ks < 2; ks++) {
            v8bf pa = *(const v8bf*)&sP[wr * 16 + fr][ks * 32 + fo];
#pragma unroll
            for (int ct = 0; ct < 2; ct++) {
                const int dcol = wc * 32 + ct * 16 + fr;
                v8bf vbf;
#pragma unroll
                for (int i = 0; i < 8; i++) vbf[i] = sV[ks * 32 + fo + i][dcol];
                acc[ct] = mfma16(pa, vbf, acc[ct]);
            }
        }
        __syncthreads();
    }
#pragma unroll
    for (int ct = 0; ct < 2; ct++) {
#pragma unroll
        for (int r = 0; r < 4; r++) {
            const int qg = q0 + wr * 16 + (lane >> 4) * 4 + r;
            const int d = wc * 32 + ct * 16 + fr;
            ctx[(size_t)(b * S_ + qg) * D_ + h * HD_ + d] = (__bf16)acc[ct][r];
        }
    }
}

// ---------------------------------------------------------------------------
// Output projection: out = ctx @ wo^T + bias (plain bf16 MFMA, fp32 out)
// ---------------------------------------------------------------------------
__global__ __launch_bounds__(256) void k_outproj(const __bf16* __restrict__ A,
                                                 const __bf16* __restrict__ Bw,
                                                 const float* __restrict__ bias,
                                                 float* __restrict__ out) {
    __shared__ __bf16 sA[64][72], sB[64][72];
    const int n0 = blockIdx.x * 64;
    const int m0 = blockIdx.y * 64;
    const int tid = threadIdx.x, lane = tid & 63, wid = tid >> 6;
    const int fr = lane & 15, fo = (lane >> 4) * 8;
    const int srow = tid >> 2, scol = (tid & 3) * 16;
    v4f acc[4] = {};
    for (int k0 = 0; k0 < D_; k0 += 64) {
        const size_t ga = (size_t)(m0 + srow) * D_ + k0 + scol;
        const size_t gb = (size_t)(n0 + srow) * D_ + k0 + scol;
        *(v8bf*)&sA[srow][scol]     = *(const v8bf*)(A + ga);
        *(v8bf*)&sA[srow][scol + 8] = *(const v8bf*)(A + ga + 8);
        *(v8bf*)&sB[srow][scol]     = *(const v8bf*)(Bw + gb);
        *(v8bf*)&sB[srow][scol + 8] = *(const v8bf*)(Bw + gb + 8);
        __syncthreads();
#pragma unroll
        for (int ks = 0; ks < 2; ks++) {
            v8bf a = *(const v8bf*)&sA[wid * 16 + fr][ks * 32 + fo];
#pragma unroll
            for (int nt = 0; nt < 4; nt++) {
                v8bf bb = *(const v8bf*)&sB[nt * 16 + fr][ks * 32 + fo];
                acc[nt] = mfma16(a, bb, acc[nt]);
            }
        }
        __syncthreads();
    }
#pragma unroll
    for (int nt = 0; nt < 4; nt++) {
        const float bv = bias[n0 + nt * 16 + fr];
#pragma unroll
        for (int r = 0; r < 4; r++) {
            const int row = m0 + wid * 16 + (lane >> 4) * 4 + r;
            out[(size_t)row * D_ + n0 + nt * 16 + fr] = acc[nt][r] + bv;
        }
    }
}

// ---------------------------------------------------------------------------
extern "C" void kernel_launch(void* const* d_in, const int* in_sizes, int n_in,
                              void* d_out, int out_size, void* d_ws, size_t ws_size,
                              hipStream_t stream) {
    (void)in_sizes; (void)n_in; (void)out_size; (void)ws_size;
    const float* x    = (const float*)d_in[0];
    const int*   mask = (const int*)d_in[1];
    const float* wq   = (const float*)d_in[2];
    const float* wk   = (const float*)d_in[3];
    const float* wv   = (const float*)d_in[4];
    const float* wo   = (const float*)d_in[5];
    const float* wob  = (const float*)d_in[6];
    const float* rel  = (const float*)d_in[7];
    float* out  = (float*)d_out;
    float* attn = out + (size_t)B_ * S_ * D_;

    char* p = (char*)d_ws;
    auto alloc = [&](size_t bytes) -> char* {
        char* r = p;
        p += (bytes + 255) & ~(size_t)255;
        return r;
    };
    const size_t BSD = (size_t)B_ * S_ * D_;   // 4,194,304
    const size_t DD  = (size_t)D_ * D_;        // 1,048,576
    __bf16* xh   = (__bf16*)alloc(BSD * 2);
    __bf16* xl   = (__bf16*)alloc(BSD * 2);
    __bf16* wqh  = (__bf16*)alloc(DD * 2);
    __bf16* wql  = (__bf16*)alloc(DD * 2);
    __bf16* wkh  = (__bf16*)alloc(DD * 2);
    __bf16* wkl  = (__bf16*)alloc(DD * 2);
    __bf16* wvh  = (__bf16*)alloc(DD * 2);
    __bf16* wvl  = (__bf16*)alloc(DD * 2);
    __bf16* woh  = (__bf16*)alloc(DD * 2);
    __bf16* wol  = (__bf16*)alloc(DD * 2);
    __bf16* relh = (__bf16*)alloc((size_t)NJ_ * HD_ * 2);
    __bf16* rell = (__bf16*)alloc((size_t)NJ_ * HD_ * 2);
    __bf16* Qh   = (__bf16*)alloc(BSD * 2);
    __bf16* Ql   = (__bf16*)alloc(BSD * 2);
    __bf16* Kh   = (__bf16*)alloc(BSD * 2);
    __bf16* Kl   = (__bf16*)alloc(BSD * 2);
    __bf16* Vb   = (__bf16*)alloc(BSD * 2);
    float*  Rg   = (float*)alloc((size_t)B_ * H_ * S_ * RSTRIDE_ * 4);
    float*  mrow = (float*)alloc((size_t)B_ * H_ * S_ * 4);
    float*  lrow = (float*)alloc((size_t)B_ * H_ * S_ * 4);
    __bf16* ctx  = (__bf16*)alloc(BSD * 2);
    unsigned char* flags = (unsigned char*)alloc((size_t)B_ * S_);

    // 1) splits
    k_split2<<<2048, 256, 0, stream>>>(x, xh, xl, (int)(BSD / 4));
    k_split2<<<1024, 256, 0, stream>>>(wq, wqh, wql, (int)(DD / 4));
    k_split2<<<1024, 256, 0, stream>>>(wk, wkh, wkl, (int)(DD / 4));
    k_split2<<<1024, 256, 0, stream>>>(wv, wvh, wvl, (int)(DD / 4));
    k_split2<<<1024, 256, 0, stream>>>(wo, woh, wol, (int)(DD / 4));
    k_split2<<<17, 256, 0, stream>>>(rel, relh, rell, (int)(NJ_ * HD_ / 4));

    // 2) mask row flags
    k_rowflag<<<B_ * S_, 256, 0, stream>>>(mask, flags);

    // 3) projections
    k_proj<0><<<dim3(D_ / 64, B_ * S_ / 64), 256, 0, stream>>>(xh, xl, wqh, wql, Qh, Ql);
    k_proj<0><<<dim3(D_ / 64, B_ * S_ / 64), 256, 0, stream>>>(xh, xl, wkh, wkl, Kh, Kl);
    k_proj<1><<<dim3(D_ / 64, B_ * S_ / 64), 256, 0, stream>>>(xh, xl, wvh, wvl, Vb, nullptr);

    // 4) rel bias table R
    k_relgemm<<<dim3(S_ / 64, B_ * H_), 256, 0, stream>>>(Qh, Ql, relh, rell, Rg);

    // 5) raw scores + online softmax stats
    k_scores<<<dim3(S_ / 64, B_ * H_), 512, 0, stream>>>(Qh, Ql, Kh, Kl, Rg, mask, flags,
                                                         attn, mrow, lrow);

    // 6) softmax finalize (attn in place) + PV
    k_pv<<<dim3(S_ / 64, B_ * H_), 512, 0, stream>>>(Vb, mrow, lrow, attn, ctx);

    // 7) output projection
    k_outproj<<<dim3(D_ / 64, B_ * S_ / 64), 256, 0, stream>>>(ctx, woh, wob, out);
}

// Round 2
// 697.708 us; speedup vs baseline: 1.2252x; 1.2252x over previous
//
#include <hip/hip_runtime.h>
#include <hip/hip_bf16.h>

// Problem constants
#define B_ 2
#define S_ 2048
#define H_ 16
#define HD_ 64
#define D_ 1024
#define NJ_ 257      // 2*MAX_REL+1
#define RSTRIDE_ 264 // padded row stride for R (16B aligned)

typedef __bf16 v8bf __attribute__((ext_vector_type(8)));
typedef __bf16 v4bf __attribute__((ext_vector_type(4)));
typedef float  v4f  __attribute__((ext_vector_type(4)));

static __device__ __forceinline__ v4f mfma16(v8bf a, v8bf b, v4f c) {
    return __builtin_amdgcn_mfma_f32_16x16x32_bf16(a, b, c, 0, 0, 0);
}

// ---------------------------------------------------------------------------
// Split fp32 -> bf16 hi + bf16 lo
// ---------------------------------------------------------------------------
__global__ void k_split2(const float* __restrict__ src, __bf16* __restrict__ h,
                         __bf16* __restrict__ l, int n4) {
    int i = blockIdx.x * blockDim.x + threadIdx.x;
    int stride = gridDim.x * blockDim.x;
    for (; i < n4; i += stride) {
        const float4 v = ((const float4*)src)[i];
        float vv[4] = {v.x, v.y, v.z, v.w};
        v4bf hv, lv;
#pragma unroll
        for (int j = 0; j < 4; j++) {
            __bf16 hb = (__bf16)vv[j];
            hv[j] = hb;
            lv[j] = (__bf16)(vv[j] - (float)hb);
        }
        *(v4bf*)(h + 4 * (size_t)i) = hv;
        *(v4bf*)(l + 4 * (size_t)i) = lv;
    }
}

// ---------------------------------------------------------------------------
// Per-(b,q) row flag: 1 if whole mask row is nonzero
// ---------------------------------------------------------------------------
__global__ void k_rowflag(const int* __restrict__ mask, unsigned char* __restrict__ flags) {
    const int row = blockIdx.x;
    const int4* mp = (const int4*)(mask + (size_t)row * S_);
    int ok = 1;
    for (int i = threadIdx.x; i < S_ / 4; i += blockDim.x) {
        int4 m = mp[i];
        ok &= (m.x != 0) & (m.y != 0) & (m.z != 0) & (m.w != 0);
    }
    int all = __syncthreads_and(ok);
    if (threadIdx.x == 0) flags[row] = (unsigned char)(all != 0);
}

// ---------------------------------------------------------------------------
// Projection GEMM (3-term split, hi/lo bf16 outputs) for Q and K
// ---------------------------------------------------------------------------
__global__ __launch_bounds__(256) void k_proj(const __bf16* __restrict__ Ah,
                                              const __bf16* __restrict__ Al,
                                              const __bf16* __restrict__ Bh,
                                              const __bf16* __restrict__ Bl,
                                              __bf16* __restrict__ Oh,
                                              __bf16* __restrict__ Ol) {
    __shared__ __bf16 sAh[64][72], sAl[64][72], sBh[64][72], sBl[64][72];
    const int n0 = blockIdx.x * 64;
    const int m0 = blockIdx.y * 64;
    const int tid = threadIdx.x, lane = tid & 63, wid = tid >> 6;
    const int fr = lane & 15, fo = (lane >> 4) * 8;
    const int srow = tid >> 2, scol = (tid & 3) * 16;
    v4f acc[4] = {};
    for (int k0 = 0; k0 < D_; k0 += 64) {
        const size_t ga = (size_t)(m0 + srow) * D_ + k0 + scol;
        const size_t gb = (size_t)(n0 + srow) * D_ + k0 + scol;
        *(v8bf*)&sAh[srow][scol]     = *(const v8bf*)(Ah + ga);
        *(v8bf*)&sAh[srow][scol + 8] = *(const v8bf*)(Ah + ga + 8);
        *(v8bf*)&sAl[srow][scol]     = *(const v8bf*)(Al + ga);
        *(v8bf*)&sAl[srow][scol + 8] = *(const v8bf*)(Al + ga + 8);
        *(v8bf*)&sBh[srow][scol]     = *(const v8bf*)(Bh + gb);
        *(v8bf*)&sBh[srow][scol + 8] = *(const v8bf*)(Bh + gb + 8);
        *(v8bf*)&sBl[srow][scol]     = *(const v8bf*)(Bl + gb);
        *(v8bf*)&sBl[srow][scol + 8] = *(const v8bf*)(Bl + gb + 8);
        __syncthreads();
#pragma unroll
        for (int ks = 0; ks < 2; ks++) {
            v8bf ah = *(const v8bf*)&sAh[wid * 16 + fr][ks * 32 + fo];
            v8bf al = *(const v8bf*)&sAl[wid * 16 + fr][ks * 32 + fo];
#pragma unroll
            for (int nt = 0; nt < 4; nt++) {
                v8bf bh = *(const v8bf*)&sBh[nt * 16 + fr][ks * 32 + fo];
                v8bf bl = *(const v8bf*)&sBl[nt * 16 + fr][ks * 32 + fo];
                acc[nt] = mfma16(ah, bh, acc[nt]);
                acc[nt] = mfma16(ah, bl, acc[nt]);
                acc[nt] = mfma16(al, bh, acc[nt]);
            }
        }
        __syncthreads();
    }
#pragma unroll
    for (int nt = 0; nt < 4; nt++) {
#pragma unroll
        for (int r = 0; r < 4; r++) {
            const int row = m0 + wid * 16 + (lane >> 4) * 4 + r;
            const int col = n0 + nt * 16 + fr;
            const size_t idx = (size_t)row * D_ + col;
            float f = acc[nt][r];
            __bf16 hb = (__bf16)f;
            Oh[idx] = hb;
            Ol[idx] = (__bf16)(f - (float)hb);
        }
    }
}

// ---------------------------------------------------------------------------
// Plain 1-term bf16 projection (V): O = A @ B^T, bf16 out
// ---------------------------------------------------------------------------
__global__ __launch_bounds__(256) void k_projV(const __bf16* __restrict__ A,
                                               const __bf16* __restrict__ Bw,
                                               __bf16* __restrict__ O) {
    __shared__ __bf16 sA[64][72], sB[64][72];
    const int n0 = blockIdx.x * 64;
    const int m0 = blockIdx.y * 64;
    const int tid = threadIdx.x, lane = tid & 63, wid = tid >> 6;
    const int fr = lane & 15, fo = (lane >> 4) * 8;
    const int srow = tid >> 2, scol = (tid & 3) * 16;
    v4f acc[4] = {};
    for (int k0 = 0; k0 < D_; k0 += 64) {
        const size_t ga = (size_t)(m0 + srow) * D_ + k0 + scol;
        const size_t gb = (size_t)(n0 + srow) * D_ + k0 + scol;
        *(v8bf*)&sA[srow][scol]     = *(const v8bf*)(A + ga);
        *(v8bf*)&sA[srow][scol + 8] = *(const v8bf*)(A + ga + 8);
        *(v8bf*)&sB[srow][scol]     = *(const v8bf*)(Bw + gb);
        *(v8bf*)&sB[srow][scol + 8] = *(const v8bf*)(Bw + gb + 8);
        __syncthreads();
#pragma unroll
        for (int ks = 0; ks < 2; ks++) {
            v8bf a = *(const v8bf*)&sA[wid * 16 + fr][ks * 32 + fo];
#pragma unroll
            for (int nt = 0; nt < 4; nt++) {
                v8bf bb = *(const v8bf*)&sB[nt * 16 + fr][ks * 32 + fo];
                acc[nt] = mfma16(a, bb, acc[nt]);
            }
        }
        __syncthreads();
    }
#pragma unroll
    for (int nt = 0; nt < 4; nt++) {
#pragma unroll
        for (int r = 0; r < 4; r++) {
            const int row = m0 + wid * 16 + (lane >> 4) * 4 + r;
            O[(size_t)row * D_ + n0 + nt * 16 + fr] = (__bf16)acc[nt][r];
        }
    }
}

// ---------------------------------------------------------------------------
// V transpose: Vt[(b*1024 + n)*2048 + s] = Vb[(b*2048 + s)*1024 + n]
// ---------------------------------------------------------------------------
__global__ __launch_bounds__(256) void k_vtrans(const __bf16* __restrict__ Vb,
                                                __bf16* __restrict__ Vt) {
    __shared__ __bf16 t[64][72];
    const int s0 = blockIdx.x * 64, n0 = blockIdx.y * 64, b = blockIdx.z;
    const int tid = threadIdx.x;
    const int r = tid >> 2, c = (tid & 3) * 16;
    const size_t gin = ((size_t)(b * S_ + s0 + r)) * D_ + n0 + c;
    *(v8bf*)&t[r][c]     = *(const v8bf*)(Vb + gin);
    *(v8bf*)&t[r][c + 8] = *(const v8bf*)(Vb + gin + 8);
    __syncthreads();
    v8bf o0, o1;
#pragma unroll
    for (int j = 0; j < 8; j++) { o0[j] = t[c + j][r]; o1[j] = t[c + 8 + j][r]; }
    const size_t gout = ((size_t)(b * D_ + n0 + r)) * S_ + s0 + c;
    *(v8bf*)(Vt + gout)     = o0;
    *(v8bf*)(Vt + gout + 8) = o1;
}

// ---------------------------------------------------------------------------
// Rel-bias GEMM: R[bh*S + q][j] = sum_d Q[b,q,h*64+d] * rel[j][d]
// ---------------------------------------------------------------------------
__global__ __launch_bounds__(256) void k_relgemm(const __bf16* __restrict__ Qh,
                                                 const __bf16* __restrict__ Ql,
                                                 const __bf16* __restrict__ relh,
                                                 const __bf16* __restrict__ rell,
                                                 float* __restrict__ Rg) {
    const int q0 = blockIdx.x * 64;
    const int bh = blockIdx.y;
    const int b = bh >> 4, h = bh & 15;
    const int tid = threadIdx.x, lane = tid & 63, wid = tid >> 6;
    const int fr = lane & 15, fo = (lane >> 4) * 8;
    const size_t qbase = (size_t)(b * S_ + q0 + wid * 16 + fr) * D_ + h * HD_;
    v8bf qa_h[2], qa_l[2];
#pragma unroll
    for (int ks = 0; ks < 2; ks++) {
        qa_h[ks] = *(const v8bf*)(Qh + qbase + ks * 32 + fo);
        qa_l[ks] = *(const v8bf*)(Ql + qbase + ks * 32 + fo);
    }
    v4f acc[17] = {};
#pragma unroll
    for (int jt = 0; jt < 17; jt++) {
        int j = jt * 16 + fr;
        if (j > 256) j = 256;
        const size_t rb = (size_t)j * HD_;
#pragma unroll
        for (int ks = 0; ks < 2; ks++) {
            v8bf bh_ = *(const v8bf*)(relh + rb + ks * 32 + fo);
            v8bf bl_ = *(const v8bf*)(rell + rb + ks * 32 + fo);
            acc[jt] = mfma16(qa_h[ks], bh_, acc[jt]);
            acc[jt] = mfma16(qa_h[ks], bl_, acc[jt]);
            acc[jt] = mfma16(qa_l[ks], bh_, acc[jt]);
        }
    }
    const size_t rowbase = ((size_t)bh * S_ + q0 + wid * 16 + (lane >> 4) * 4) * RSTRIDE_;
#pragma unroll
    for (int jt = 0; jt < 17; jt++) {
        const int j = jt * 16 + fr;
        if (j <= 256) {
#pragma unroll
            for (int r = 0; r < 4; r++)
                Rg[rowbase + (size_t)r * RSTRIDE_ + j] = acc[jt][r];
        }
    }
}

// ---------------------------------------------------------------------------
// Fused attention: pass 1 (stats) + pass 2 (finalize p, write attn, PV).
// Block: 64 q-rows x one (b,h). 8 waves: wr=w>>1 (16 rows each), wc=w&1 (32 cols).
// ---------------------------------------------------------------------------
__global__ __launch_bounds__(512, 4) void k_attn(const __bf16* __restrict__ Qh,
                                                 const __bf16* __restrict__ Ql,
                                                 const __bf16* __restrict__ Kh,
                                                 const __bf16* __restrict__ Kl,
                                                 const __bf16* __restrict__ Vt,
                                                 const float* __restrict__ Rg,
                                                 const int* __restrict__ mask,
                                                 const unsigned char* __restrict__ flags,
                                                 float* __restrict__ attn,
                                                 __bf16* __restrict__ ctx) {
    __shared__ __bf16 sKh[64][72], sKl[64][72], sVt[64][72], sP[64][72];
    __shared__ float pm[2][64], pl[2][64];
    const int qt = blockIdx.x;
    const int q0 = qt * 64;
    const int bh = blockIdx.y;
    const int b = bh >> 4, h = bh & 15;
    const int tid = threadIdx.x, lane = tid & 63, w = tid >> 6;
    const int wr = w >> 1, wc = w & 1;
    const int fr = lane & 15, fo = (lane >> 4) * 8;
    const int myrow = wr * 16 + (lane >> 4) * 4;
    const int srow = tid >> 3, sc8 = (tid & 7) * 8;

    // Hoist Q fragments (3-term split operands)
    const size_t qbase = (size_t)(b * S_ + q0 + wr * 16 + fr) * D_ + h * HD_;
    v8bf qa_h[2], qa_l[2];
#pragma unroll
    for (int ks = 0; ks < 2; ks++) {
        qa_h[ks] = *(const v8bf*)(Qh + qbase + ks * 32 + fo);
        qa_l[ks] = *(const v8bf*)(Ql + qbase + ks * 32 + fo);
    }

    // Hoist per-row constants: clipped rel-bias ends, mask flags, bases
    float rcL[4], rcR[4];
    int flr[4];
    size_t rbase[4], abase[4], mbase[4];
#pragma unroll
    for (int r = 0; r < 4; r++) {
        const int qg = q0 + myrow + r;
        rbase[r] = ((size_t)bh * S_ + qg) * RSTRIDE_;
        abase[r] = ((size_t)bh * S_ + qg) * S_;
        mbase[r] = ((size_t)b * S_ + qg) * S_;
        rcL[r] = Rg[rbase[r] + 0];
        rcR[r] = Rg[rbase[r] + 256];
        flr[r] = flags[b * S_ + qg];
    }

    float mrun[4], lrun[4];
#pragma unroll
    for (int r = 0; r < 4; r++) { mrun[r] = -3.0e38f; lrun[r] = 0.0f; }

    // ---------------- PASS 1: stats ----------------
    for (int kc = 0; kc < 32; kc++) {
        const int k0 = kc * 64;
        {
            const size_t gk = (size_t)(b * S_ + k0 + srow) * D_ + h * HD_ + sc8;
            *(v8bf*)&sKh[srow][sc8] = *(const v8bf*)(Kh + gk);
            *(v8bf*)&sKl[srow][sc8] = *(const v8bf*)(Kl + gk);
        }
        __syncthreads();

        v4f acc[2] = {};
#pragma unroll
        for (int ct = 0; ct < 2; ct++) {
#pragma unroll
            for (int ks = 0; ks < 2; ks++) {
                v8bf kb_h = *(const v8bf*)&sKh[wc * 32 + ct * 16 + fr][ks * 32 + fo];
                v8bf kb_l = *(const v8bf*)&sKl[wc * 32 + ct * 16 + fr][ks * 32 + fo];
                acc[ct] = mfma16(qa_h[ks], kb_h, acc[ct]);
                acc[ct] = mfma16(qa_h[ks], kb_l, acc[ct]);
                acc[ct] = mfma16(qa_l[ks], kb_h, acc[ct]);
            }
        }

        const bool band = (kc >= qt - 2) && (kc <= qt + 2);
#pragma unroll
        for (int r = 0; r < 4; r++) {
            const int qg = q0 + myrow + r;
            float s0, s1;
#pragma unroll
            for (int ct = 0; ct < 2; ct++) {
                const int k = k0 + wc * 32 + ct * 16 + fr;
                float bias;
                if (band) {
                    const int dd = k - qg;
                    const int j = dd < -128 ? 0 : (dd > 128 ? 256 : dd + 128);
                    bias = Rg[rbase[r] + j];
                } else {
                    bias = (kc < qt) ? rcL[r] : rcR[r];
                }
                float s = acc[ct][r] * 0.125f + bias;
                if (!flr[r] && mask[mbase[r] + k] == 0) s = -1e9f;
                if (ct == 0) s0 = s; else s1 = s;
            }
            const float cm = fmaxf(s0, s1);
            if (cm > mrun[r]) {
                lrun[r] *= __expf(mrun[r] - cm);
                mrun[r] = cm;
            }
            lrun[r] += __expf(s0 - mrun[r]) + __expf(s1 - mrun[r]);
        }
        __syncthreads();
    }

    // Reduce across the 16 lanes of each row group
#pragma unroll
    for (int r = 0; r < 4; r++) {
#pragma unroll
        for (int sh = 1; sh < 16; sh <<= 1) {
            const float om = __shfl_xor(mrun[r], sh);
            const float ol = __shfl_xor(lrun[r], sh);
            const float mn = fmaxf(mrun[r], om);
            lrun[r] = lrun[r] * __expf(mrun[r] - mn) + ol * __expf(om - mn);
            mrun[r] = mn;
        }
    }
    if (fr == 0) {
#pragma unroll
        for (int r = 0; r < 4; r++) {
            pm[wc][myrow + r] = mrun[r];
            pl[wc][myrow + r] = lrun[r];
        }
    }
    __syncthreads();
    float mfin[4], lfin[4];
#pragma unroll
    for (int r = 0; r < 4; r++) {
        const float m0v = pm[0][myrow + r], m1v = pm[1][myrow + r];
        const float M = fmaxf(m0v, m1v);
        const float L = pl[0][myrow + r] * __expf(m0v - M) + pl[1][myrow + r] * __expf(m1v - M);
        mfin[r] = M;
        lfin[r] = 1.0f / L;
    }

    // ---------------- PASS 2: finalize + write attn + PV ----------------
    v4f acc2[2] = {};
    for (int kc = 0; kc < 32; kc++) {
        const int k0 = kc * 64;
        __syncthreads(); // prev PV reads (and pass-1 tail) done before restage
        {
            const size_t gk = (size_t)(b * S_ + k0 + srow) * D_ + h * HD_ + sc8;
            *(v8bf*)&sKh[srow][sc8] = *(const v8bf*)(Kh + gk);
            *(v8bf*)&sKl[srow][sc8] = *(const v8bf*)(Kl + gk);
            *(v8bf*)&sVt[srow][sc8] =
                *(const v8bf*)(Vt + (size_t)(b * D_ + h * HD_ + srow) * S_ + k0 + sc8);
        }
        __syncthreads();

        v4f acc[2] = {};
#pragma unroll
        for (int ct = 0; ct < 2; ct++) {
#pragma unroll
            for (int ks = 0; ks < 2; ks++) {
                v8bf kb_h = *(const v8bf*)&sKh[wc * 32 + ct * 16 + fr][ks * 32 + fo];
                v8bf kb_l = *(const v8bf*)&sKl[wc * 32 + ct * 16 + fr][ks * 32 + fo];
                acc[ct] = mfma16(qa_h[ks], kb_h, acc[ct]);
                acc[ct] = mfma16(qa_h[ks], kb_l, acc[ct]);
                acc[ct] = mfma16(qa_l[ks], kb_h, acc[ct]);
            }
        }

        const bool band = (kc >= qt - 2) && (kc <= qt + 2);
#pragma unroll
        for (int r = 0; r < 4; r++) {
            const int qg = q0 + myrow + r;
#pragma unroll
            for (int ct = 0; ct < 2; ct++) {
                const int k = k0 + wc * 32 + ct * 16 + fr;
                float bias;
                if (band) {
                    const int dd = k - qg;
                    const int j = dd < -128 ? 0 : (dd > 128 ? 256 : dd + 128);
                    bias = Rg[rbase[r] + j];
                } else {
                    bias = (kc < qt) ? rcL[r] : rcR[r];
                }
                float s = acc[ct][r] * 0.125f + bias;
                if (!flr[r] && mask[mbase[r] + k] == 0) s = -1e9f;
                const float p = __expf(s - mfin[r]) * lfin[r];
                attn[abase[r] + k] = p;
                sP[myrow + r][wc * 32 + ct * 16 + fr] = (__bf16)p;
            }
        }
        __syncthreads();

#pragma unroll
        for (int ks = 0; ks < 2; ks++) {
            v8bf pa = *(const v8bf*)&sP[wr * 16 + fr][ks * 32 + fo];
#pragma unroll
            for (int ct = 0; ct < 2; ct++) {
                v8bf vtb = *(const v8bf*)&sVt[wc * 32 + ct * 16 + fr][ks * 32 + fo];
                acc2[ct] = mfma16(pa, vtb, acc2[ct]);
            }
        }
    }

#pragma unroll
    for (int ct = 0; ct < 2; ct++) {
#pragma unroll
        for (int r = 0; r < 4; r++) {
            const int qg = q0 + wr * 16 + (lane >> 4) * 4 + r;
            const int d = wc * 32 + ct * 16 + fr;
            ctx[(size_t)(b * S_ + qg) * D_ + h * HD_ + d] = (__bf16)acc2[ct][r];
        }
    }
}

// ---------------------------------------------------------------------------
// Output projection: out = ctx @ wo^T + bias (plain bf16 MFMA, fp32 out)
// ---------------------------------------------------------------------------
__global__ __launch_bounds__(256) void k_outproj(const __bf16* __restrict__ A,
                                                 const __bf16* __restrict__ Bw,
                                                 const float* __restrict__ bias,
                                                 float* __restrict__ out) {
    __shared__ __bf16 sA[64][72], sB[64][72];
    const int n0 = blockIdx.x * 64;
    const int m0 = blockIdx.y * 64;
    const int tid = threadIdx.x, lane = tid & 63, wid = tid >> 6;
    const int fr = lane & 15, fo = (lane >> 4) * 8;
    const int srow = tid >> 2, scol = (tid & 3) * 16;
    v4f acc[4] = {};
    for (int k0 = 0; k0 < D_; k0 += 64) {
        const size_t ga = (size_t)(m0 + srow) * D_ + k0 + scol;
        const size_t gb = (size_t)(n0 + srow) * D_ + k0 + scol;
        *(v8bf*)&sA[srow][scol]     = *(const v8bf*)(A + ga);
        *(v8bf*)&sA[srow][scol + 8] = *(const v8bf*)(A + ga + 8);
        *(v8bf*)&sB[srow][scol]     = *(const v8bf*)(Bw + gb);
        *(v8bf*)&sB[srow][scol + 8] = *(const v8bf*)(Bw + gb + 8);
        __syncthreads();
#pragma unroll
        for (int ks = 0; ks < 2; ks++) {
            v8bf a = *(const v8bf*)&sA[wid * 16 + fr][ks * 32 + fo];
#pragma unroll
            for (int nt = 0; nt < 4; nt++) {
                v8bf bb = *(const v8bf*)&sB[nt * 16 + fr][ks * 32 + fo];
                acc[nt] = mfma16(a, bb, acc[nt]);
            }
        }
        __syncthreads();
    }
#pragma unroll
    for (int nt = 0; nt < 4; nt++) {
        const float bv = bias[n0 + nt * 16 + fr];
#pragma unroll
        for (int r = 0; r < 4; r++) {
            const int row = m0 + wid * 16 + (lane >> 4) * 4 + r;
            out[(size_t)row * D_ + n0 + nt * 16 + fr] = acc[nt][r] + bv;
        }
    }
}

// ---------------------------------------------------------------------------
extern "C" void kernel_launch(void* const* d_in, const int* in_sizes, int n_in,
                              void* d_out, int out_size, void* d_ws, size_t ws_size,
                              hipStream_t stream) {
    (void)in_sizes; (void)n_in; (void)out_size; (void)ws_size;
    const float* x    = (const float*)d_in[0];
    const int*   mask = (const int*)d_in[1];
    const float* wq   = (const float*)d_in[2];
    const float* wk   = (const float*)d_in[3];
    const float* wv   = (const float*)d_in[4];
    const float* wo   = (const float*)d_in[5];
    const float* wob  = (const float*)d_in[6];
    const float* rel  = (const float*)d_in[7];
    float* out  = (float*)d_out;
    float* attn = out + (size_t)B_ * S_ * D_;

    char* p = (char*)d_ws;
    auto alloc = [&](size_t bytes) -> char* {
        char* r = p;
        p += (bytes + 255) & ~(size_t)255;
        return r;
    };
    const size_t BSD = (size_t)B_ * S_ * D_;
    const size_t DD  = (size_t)D_ * D_;
    __bf16* xh   = (__bf16*)alloc(BSD * 2);
    __bf16* xl   = (__bf16*)alloc(BSD * 2);
    __bf16* wqh  = (__bf16*)alloc(DD * 2);
    __bf16* wql  = (__bf16*)alloc(DD * 2);
    __bf16* wkh  = (__bf16*)alloc(DD * 2);
    __bf16* wkl  = (__bf16*)alloc(DD * 2);
    __bf16* wvh  = (__bf16*)alloc(DD * 2);
    __bf16* wvl  = (__bf16*)alloc(DD * 2);
    __bf16* woh  = (__bf16*)alloc(DD * 2);
    __bf16* wol  = (__bf16*)alloc(DD * 2);
    __bf16* relh = (__bf16*)alloc((size_t)NJ_ * HD_ * 2);
    __bf16* rell = (__bf16*)alloc((size_t)NJ_ * HD_ * 2);
    __bf16* Qh   = (__bf16*)alloc(BSD * 2);
    __bf16* Ql   = (__bf16*)alloc(BSD * 2);
    __bf16* Kh   = (__bf16*)alloc(BSD * 2);
    __bf16* Kl   = (__bf16*)alloc(BSD * 2);
    __bf16* Vb   = (__bf16*)alloc(BSD * 2);
    __bf16* Vt   = (__bf16*)alloc(BSD * 2);
    float*  Rg   = (float*)alloc((size_t)B_ * H_ * S_ * RSTRIDE_ * 4);
    __bf16* ctx  = (__bf16*)alloc(BSD * 2);
    unsigned char* flags = (unsigned char*)alloc((size_t)B_ * S_);

    // 1) splits
    k_split2<<<2048, 256, 0, stream>>>(x, xh, xl, (int)(BSD / 4));
    k_split2<<<1024, 256, 0, stream>>>(wq, wqh, wql, (int)(DD / 4));
    k_split2<<<1024, 256, 0, stream>>>(wk, wkh, wkl, (int)(DD / 4));
    k_split2<<<1024, 256, 0, stream>>>(wv, wvh, wvl, (int)(DD / 4));
    k_split2<<<1024, 256, 0, stream>>>(wo, woh, wol, (int)(DD / 4));
    k_split2<<<17, 256, 0, stream>>>(rel, relh, rell, (int)(NJ_ * HD_ / 4));

    // 2) mask row flags
    k_rowflag<<<B_ * S_, 256, 0, stream>>>(mask, flags);

    // 3) projections (Q,K split; V plain)
    k_proj<<<dim3(D_ / 64, B_ * S_ / 64), 256, 0, stream>>>(xh, xl, wqh, wql, Qh, Ql);
    k_proj<<<dim3(D_ / 64, B_ * S_ / 64), 256, 0, stream>>>(xh, xl, wkh, wkl, Kh, Kl);
    k_projV<<<dim3(D_ / 64, B_ * S_ / 64), 256, 0, stream>>>(xh, wvh, Vb);

    // 4) V transpose for PV B-operand
    k_vtrans<<<dim3(S_ / 64, D_ / 64, B_), 256, 0, stream>>>(Vb, Vt);

    // 5) rel bias table R
    k_relgemm<<<dim3(S_ / 64, B_ * H_), 256, 0, stream>>>(Qh, Ql, relh, rell, Rg);

    // 6) fused attention (stats + finalize + attn write + PV)
    k_attn<<<dim3(S_ / 64, B_ * H_), 512, 0, stream>>>(Qh, Ql, Kh, Kl, Vt, Rg, mask, flags,
                                                       attn, ctx);

    // 7) output projection
    k_outproj<<<dim3(D_ / 64, B_ * S_ / 64), 256, 0, stream>>>(ctx, woh, wob, out);
}

// Round 4
// 608.944 us; speedup vs baseline: 1.4038x; 1.1458x over previous
//
#include <hip/hip_runtime.h>
#include <hip/hip_bf16.h>

// Problem constants
#define B_ 2
#define S_ 2048
#define H_ 16
#define HD_ 64
#define D_ 1024
#define NJ_ 257      // 2*MAX_REL+1
#define RSTRIDE_ 264 // padded row stride for R (16B aligned)

typedef __bf16 v8bf __attribute__((ext_vector_type(8)));
typedef __bf16 v4bf __attribute__((ext_vector_type(4)));
typedef float  v4f  __attribute__((ext_vector_type(4)));

static __device__ __forceinline__ v4f mfma16(v8bf a, v8bf b, v4f c) {
    return __builtin_amdgcn_mfma_f32_16x16x32_bf16(a, b, c, 0, 0, 0);
}

// ---------------------------------------------------------------------------
// Split fp32 -> bf16 hi + bf16 lo
// ---------------------------------------------------------------------------
__global__ void k_split2(const float* __restrict__ src, __bf16* __restrict__ h,
                         __bf16* __restrict__ l, int n4) {
    int i = blockIdx.x * blockDim.x + threadIdx.x;
    int stride = gridDim.x * blockDim.x;
    for (; i < n4; i += stride) {
        const float4 v = ((const float4*)src)[i];
        float vv[4] = {v.x, v.y, v.z, v.w};
        v4bf hv, lv;
#pragma unroll
        for (int j = 0; j < 4; j++) {
            __bf16 hb = (__bf16)vv[j];
            hv[j] = hb;
            lv[j] = (__bf16)(vv[j] - (float)hb);
        }
        *(v4bf*)(h + 4 * (size_t)i) = hv;
        *(v4bf*)(l + 4 * (size_t)i) = lv;
    }
}

// ---------------------------------------------------------------------------
// Per-(b,q) row flag: 1 if whole mask row is nonzero
// ---------------------------------------------------------------------------
__global__ void k_rowflag(const int* __restrict__ mask, unsigned char* __restrict__ flags) {
    const int row = blockIdx.x;
    const int4* mp = (const int4*)(mask + (size_t)row * S_);
    int ok = 1;
    for (int i = threadIdx.x; i < S_ / 4; i += blockDim.x) {
        int4 m = mp[i];
        ok &= (m.x != 0) & (m.y != 0) & (m.z != 0) & (m.w != 0);
    }
    int all = __syncthreads_and(ok);
    if (threadIdx.x == 0) flags[row] = (unsigned char)(all != 0);
}

// ---------------------------------------------------------------------------
// Projection GEMM (3-term split, hi/lo bf16 outputs) for Q and K
// ---------------------------------------------------------------------------
__global__ __launch_bounds__(256) void k_proj(const __bf16* __restrict__ Ah,
                                              const __bf16* __restrict__ Al,
                                              const __bf16* __restrict__ Bh,
                                              const __bf16* __restrict__ Bl,
                                              __bf16* __restrict__ Oh,
                                              __bf16* __restrict__ Ol) {
    __shared__ __bf16 sAh[64][72], sAl[64][72], sBh[64][72], sBl[64][72];
    const int n0 = blockIdx.x * 64;
    const int m0 = blockIdx.y * 64;
    const int tid = threadIdx.x, lane = tid & 63, wid = tid >> 6;
    const int fr = lane & 15, fo = (lane >> 4) * 8;
    const int srow = tid >> 2, scol = (tid & 3) * 16;
    v4f acc[4] = {};
    for (int k0 = 0; k0 < D_; k0 += 64) {
        const size_t ga = (size_t)(m0 + srow) * D_ + k0 + scol;
        const size_t gb = (size_t)(n0 + srow) * D_ + k0 + scol;
        *(v8bf*)&sAh[srow][scol]     = *(const v8bf*)(Ah + ga);
        *(v8bf*)&sAh[srow][scol + 8] = *(const v8bf*)(Ah + ga + 8);
        *(v8bf*)&sAl[srow][scol]     = *(const v8bf*)(Al + ga);
        *(v8bf*)&sAl[srow][scol + 8] = *(const v8bf*)(Al + ga + 8);
        *(v8bf*)&sBh[srow][scol]     = *(const v8bf*)(Bh + gb);
        *(v8bf*)&sBh[srow][scol + 8] = *(const v8bf*)(Bh + gb + 8);
        *(v8bf*)&sBl[srow][scol]     = *(const v8bf*)(Bl + gb);
        *(v8bf*)&sBl[srow][scol + 8] = *(const v8bf*)(Bl + gb + 8);
        __syncthreads();
#pragma unroll
        for (int ks = 0; ks < 2; ks++) {
            v8bf ah = *(const v8bf*)&sAh[wid * 16 + fr][ks * 32 + fo];
            v8bf al = *(const v8bf*)&sAl[wid * 16 + fr][ks * 32 + fo];
#pragma unroll
            for (int nt = 0; nt < 4; nt++) {
                v8bf bh = *(const v8bf*)&sBh[nt * 16 + fr][ks * 32 + fo];
                v8bf bl = *(const v8bf*)&sBl[nt * 16 + fr][ks * 32 + fo];
                acc[nt] = mfma16(ah, bh, acc[nt]);
                acc[nt] = mfma16(ah, bl, acc[nt]);
                acc[nt] = mfma16(al, bh, acc[nt]);
            }
        }
        __syncthreads();
    }
#pragma unroll
    for (int nt = 0; nt < 4; nt++) {
#pragma unroll
        for (int r = 0; r < 4; r++) {
            const int row = m0 + wid * 16 + (lane >> 4) * 4 + r;
            const int col = n0 + nt * 16 + fr;
            const size_t idx = (size_t)row * D_ + col;
            float f = acc[nt][r];
            __bf16 hb = (__bf16)f;
            Oh[idx] = hb;
            Ol[idx] = (__bf16)(f - (float)hb);
        }
    }
}

// ---------------------------------------------------------------------------
// Plain 1-term bf16 projection (V): O = A @ B^T, bf16 out
// ---------------------------------------------------------------------------
__global__ __launch_bounds__(256) void k_projV(const __bf16* __restrict__ A,
                                               const __bf16* __restrict__ Bw,
                                               __bf16* __restrict__ O) {
    __shared__ __bf16 sA[64][72], sB[64][72];
    const int n0 = blockIdx.x * 64;
    const int m0 = blockIdx.y * 64;
    const int tid = threadIdx.x, lane = tid & 63, wid = tid >> 6;
    const int fr = lane & 15, fo = (lane >> 4) * 8;
    const int srow = tid >> 2, scol = (tid & 3) * 16;
    v4f acc[4] = {};
    for (int k0 = 0; k0 < D_; k0 += 64) {
        const size_t ga = (size_t)(m0 + srow) * D_ + k0 + scol;
        const size_t gb = (size_t)(n0 + srow) * D_ + k0 + scol;
        *(v8bf*)&sA[srow][scol]     = *(const v8bf*)(A + ga);
        *(v8bf*)&sA[srow][scol + 8] = *(const v8bf*)(A + ga + 8);
        *(v8bf*)&sB[srow][scol]     = *(const v8bf*)(Bw + gb);
        *(v8bf*)&sB[srow][scol + 8] = *(const v8bf*)(Bw + gb + 8);
        __syncthreads();
#pragma unroll
        for (int ks = 0; ks < 2; ks++) {
            v8bf a = *(const v8bf*)&sA[wid * 16 + fr][ks * 32 + fo];
#pragma unroll
            for (int nt = 0; nt < 4; nt++) {
                v8bf bb = *(const v8bf*)&sB[nt * 16 + fr][ks * 32 + fo];
                acc[nt] = mfma16(a, bb, acc[nt]);
            }
        }
        __syncthreads();
    }
#pragma unroll
    for (int nt = 0; nt < 4; nt++) {
#pragma unroll
        for (int r = 0; r < 4; r++) {
            const int row = m0 + wid * 16 + (lane >> 4) * 4 + r;
            O[(size_t)row * D_ + n0 + nt * 16 + fr] = (__bf16)acc[nt][r];
        }
    }
}

// ---------------------------------------------------------------------------
// V transpose: Vt[(b*1024 + n)*2048 + s] = Vb[(b*2048 + s)*1024 + n]
// ---------------------------------------------------------------------------
__global__ __launch_bounds__(256) void k_vtrans(const __bf16* __restrict__ Vb,
                                                __bf16* __restrict__ Vt) {
    __shared__ __bf16 t[64][72];
    const int s0 = blockIdx.x * 64, n0 = blockIdx.y * 64, b = blockIdx.z;
    const int tid = threadIdx.x;
    const int r = tid >> 2, c = (tid & 3) * 16;
    const size_t gin = ((size_t)(b * S_ + s0 + r)) * D_ + n0 + c;
    *(v8bf*)&t[r][c]     = *(const v8bf*)(Vb + gin);
    *(v8bf*)&t[r][c + 8] = *(const v8bf*)(Vb + gin + 8);
    __syncthreads();
    v8bf o0, o1;
#pragma unroll
    for (int j = 0; j < 8; j++) { o0[j] = t[c + j][r]; o1[j] = t[c + 8 + j][r]; }
    const size_t gout = ((size_t)(b * D_ + n0 + r)) * S_ + s0 + c;
    *(v8bf*)(Vt + gout)     = o0;
    *(v8bf*)(Vt + gout + 8) = o1;
}

// ---------------------------------------------------------------------------
// Rel-bias GEMM: R[bh*S + q][j] = sum_d Q[b,q,h*64+d] * rel[j][d]
// ---------------------------------------------------------------------------
__global__ __launch_bounds__(256) void k_relgemm(const __bf16* __restrict__ Qh,
                                                 const __bf16* __restrict__ Ql,
                                                 const __bf16* __restrict__ relh,
                                                 const __bf16* __restrict__ rell,
                                                 float* __restrict__ Rg) {
    const int q0 = blockIdx.x * 64;
    const int bh = blockIdx.y;
    const int b = bh >> 4, h = bh & 15;
    const int tid = threadIdx.x, lane = tid & 63, wid = tid >> 6;
    const int fr = lane & 15, fo = (lane >> 4) * 8;
    const size_t qbase = (size_t)(b * S_ + q0 + wid * 16 + fr) * D_ + h * HD_;
    v8bf qa_h[2], qa_l[2];
#pragma unroll
    for (int ks = 0; ks < 2; ks++) {
        qa_h[ks] = *(const v8bf*)(Qh + qbase + ks * 32 + fo);
        qa_l[ks] = *(const v8bf*)(Ql + qbase + ks * 32 + fo);
    }
    v4f acc[17] = {};
#pragma unroll
    for (int jt = 0; jt < 17; jt++) {
        int j = jt * 16 + fr;
        if (j > 256) j = 256;
        const size_t rb = (size_t)j * HD_;
#pragma unroll
        for (int ks = 0; ks < 2; ks++) {
            v8bf bh_ = *(const v8bf*)(relh + rb + ks * 32 + fo);
            v8bf bl_ = *(const v8bf*)(rell + rb + ks * 32 + fo);
            acc[jt] = mfma16(qa_h[ks], bh_, acc[jt]);
            acc[jt] = mfma16(qa_h[ks], bl_, acc[jt]);
            acc[jt] = mfma16(qa_l[ks], bh_, acc[jt]);
        }
    }
    const size_t rowbase = ((size_t)bh * S_ + q0 + wid * 16 + (lane >> 4) * 4) * RSTRIDE_;
#pragma unroll
    for (int jt = 0; jt < 17; jt++) {
        const int j = jt * 16 + fr;
        if (j <= 256) {
#pragma unroll
            for (int r = 0; r < 4; r++)
                Rg[rowbase + (size_t)r * RSTRIDE_ + j] = acc[jt][r];
        }
    }
}

// ---------------------------------------------------------------------------
// Stats pass: online per-row (m, l) over the full 2048-col score row.
// 128 q-rows/block, 8 waves, each wave owns 16 rows x all 64 chunk-cols.
// Double-buffered K LDS with register prefetch; 1 barrier per chunk.
// 2-term split QK: (q_hi + q_lo) . k_hi
// ---------------------------------------------------------------------------
__global__ __launch_bounds__(512, 4) void k_stats(const __bf16* __restrict__ Qh,
                                                  const __bf16* __restrict__ Ql,
                                                  const __bf16* __restrict__ Kh,
                                                  const float* __restrict__ Rg,
                                                  const int* __restrict__ mask,
                                                  const unsigned char* __restrict__ flags,
                                                  float* __restrict__ mrow,
                                                  float* __restrict__ lrow) {
    __shared__ __bf16 sK[2][64][72];
    const int flat = blockIdx.x;
    const int swz = (flat & 7) * 64 + (flat >> 3); // XCD-chunked bijection (512 = 8*64)
    const int qt = swz & 15, bh = swz >> 4;
    const int b = bh >> 4, h = bh & 15;
    const int q0 = qt * 128;
    const int tid = threadIdx.x, lane = tid & 63, w = tid >> 6;
    const int fr = lane & 15, fq = lane >> 4, fo = fq * 8;
    const int myrow = w * 16 + fq * 4;
    const int srow = tid >> 3, sc8 = (tid & 7) * 8;

    // Q fragments (hi+lo)
    const size_t qbase = (size_t)(b * S_ + q0 + w * 16 + fr) * D_ + h * HD_;
    v8bf qa_h[2], qa_l[2];
#pragma unroll
    for (int ks = 0; ks < 2; ks++) {
        qa_h[ks] = *(const v8bf*)(Qh + qbase + ks * 32 + fo);
        qa_l[ks] = *(const v8bf*)(Ql + qbase + ks * 32 + fo);
    }

    // Per-row constants
    const int qg0 = q0 + myrow;
    const size_t rbase0 = ((size_t)bh * S_ + qg0) * RSTRIDE_;
    const size_t mbase0 = ((size_t)b * S_ + qg0) * S_;
    float rcL[4], rcR[4];
    int flr[4];
#pragma unroll
    for (int r = 0; r < 4; r++) {
        rcL[r] = Rg[rbase0 + (size_t)r * RSTRIDE_];
        rcR[r] = Rg[rbase0 + (size_t)r * RSTRIDE_ + 256];
        flr[r] = flags[(size_t)b * S_ + qg0 + r];
    }

    const __bf16* kgbase = Kh + (size_t)(b * S_ + srow) * D_ + h * HD_ + sc8;
    // prologue: chunk 0 -> buf0; prefetch chunk 1
    v8bf rk = *(const v8bf*)(kgbase);
    *(v8bf*)&sK[0][srow][sc8] = rk;
    rk = *(const v8bf*)(kgbase + (size_t)64 * D_);
    __syncthreads();

    float mrun[4], lrun[4];
#pragma unroll
    for (int r = 0; r < 4; r++) { mrun[r] = -3.0e38f; lrun[r] = 0.0f; }

    int cur = 0;
    for (int kc = 0; kc < 32; kc++) {
        const int k0 = kc * 64;
        v4f acc[4] = {};
#pragma unroll
        for (int ct = 0; ct < 4; ct++) {
#pragma unroll
            for (int ks = 0; ks < 2; ks++) {
                v8bf kb = *(const v8bf*)&sK[cur][ct * 16 + fr][ks * 32 + fo];
                acc[ct] = mfma16(qa_h[ks], kb, acc[ct]);
                acc[ct] = mfma16(qa_l[ks], kb, acc[ct]);
            }
        }
        const bool band = (kc >= 2 * qt - 3) && (kc <= 2 * qt + 3);
        const bool left = kc < 2 * qt;
#pragma unroll
        for (int r = 0; r < 4; r++) {
            const int qg = qg0 + r;
            float s[4];
#pragma unroll
            for (int ct = 0; ct < 4; ct++) {
                const int k = k0 + ct * 16 + fr;
                float bias;
                if (band) {
                    const int dd = k - qg;
                    const int j = dd < -128 ? 0 : (dd > 128 ? 256 : dd + 128);
                    bias = Rg[rbase0 + (size_t)r * RSTRIDE_ + j];
                } else {
                    bias = left ? rcL[r] : rcR[r];
                }
                float sv = acc[ct][r] * 0.125f + bias;
                if (!flr[r] && mask[mbase0 + (size_t)r * S_ + k] == 0) sv = -1e9f;
                s[ct] = sv;
            }
            const float cm = fmaxf(fmaxf(s[0], s[1]), fmaxf(s[2], s[3]));
            if (cm > mrun[r]) {
                lrun[r] *= __expf(mrun[r] - cm);
                mrun[r] = cm;
            }
            lrun[r] += __expf(s[0] - mrun[r]) + __expf(s[1] - mrun[r]) +
                       __expf(s[2] - mrun[r]) + __expf(s[3] - mrun[r]);
        }
        if (kc < 31) *(v8bf*)&sK[cur ^ 1][srow][sc8] = rk;
        if (kc < 30) rk = *(const v8bf*)(kgbase + (size_t)(k0 + 128) * D_);
        __syncthreads();
        cur ^= 1;
    }

    // reduce across the 16 fr lanes of each row
#pragma unroll
    for (int r = 0; r < 4; r++) {
#pragma unroll
        for (int sh = 1; sh < 16; sh <<= 1) {
            const float om = __shfl_xor(mrun[r], sh);
            const float ol = __shfl_xor(lrun[r], sh);
            const float mn = fmaxf(mrun[r], om);
            lrun[r] = lrun[r] * __expf(mrun[r] - mn) + ol * __expf(om - mn);
            mrun[r] = mn;
        }
    }
    if (fr == 0) {
#pragma unroll
        for (int r = 0; r < 4; r++) {
            mrow[(size_t)bh * S_ + qg0 + r] = mrun[r];
            lrow[(size_t)bh * S_ + qg0 + r] = lrun[r];
        }
    }
}

// ---------------------------------------------------------------------------
// Final pass: recompute scores, p = exp(s-m)/l, write attn (only write),
// accumulate ctx = P @ V. Double-buffered K/Vt; 2 barriers per chunk.
// ---------------------------------------------------------------------------
__global__ __launch_bounds__(512, 4) void k_final(const __bf16* __restrict__ Qh,
                                                  const __bf16* __restrict__ Ql,
                                                  const __bf16* __restrict__ Kh,
                                                  const __bf16* __restrict__ Vt,
                                                  const float* __restrict__ Rg,
                                                  const int* __restrict__ mask,
                                                  const unsigned char* __restrict__ flags,
                                                  const float* __restrict__ mrow,
                                                  const float* __restrict__ lrow,
                                                  float* __restrict__ attn,
                                                  __bf16* __restrict__ ctx) {
    __shared__ __bf16 sK[2][64][72], sV[2][64][72], sP[128][72];
    const int flat = blockIdx.x;
    const int swz = (flat & 7) * 64 + (flat >> 3);
    const int qt = swz & 15, bh = swz >> 4;
    const int b = bh >> 4, h = bh & 15;
    const int q0 = qt * 128;
    const int tid = threadIdx.x, lane = tid & 63, w = tid >> 6;
    const int fr = lane & 15, fq = lane >> 4, fo = fq * 8;
    const int myrow = w * 16 + fq * 4;
    const int srow = tid >> 3, sc8 = (tid & 7) * 8;

    const size_t qbase = (size_t)(b * S_ + q0 + w * 16 + fr) * D_ + h * HD_;
    v8bf qa_h[2], qa_l[2];
#pragma unroll
    for (int ks = 0; ks < 2; ks++) {
        qa_h[ks] = *(const v8bf*)(Qh + qbase + ks * 32 + fo);
        qa_l[ks] = *(const v8bf*)(Ql + qbase + ks * 32 + fo);
    }

    const int qg0 = q0 + myrow;
    const size_t rbase0 = ((size_t)bh * S_ + qg0) * RSTRIDE_;
    const size_t mbase0 = ((size_t)b * S_ + qg0) * S_;
    const size_t abase0 = ((size_t)bh * S_ + qg0) * S_;
    float rcL[4], rcR[4], mfin[4], lfin[4];
    int flr[4];
#pragma unroll
    for (int r = 0; r < 4; r++) {
        rcL[r] = Rg[rbase0 + (size_t)r * RSTRIDE_];
        rcR[r] = Rg[rbase0 + (size_t)r * RSTRIDE_ + 256];
        flr[r] = flags[(size_t)b * S_ + qg0 + r];
        mfin[r] = mrow[(size_t)bh * S_ + qg0 + r];
        lfin[r] = 1.0f / lrow[(size_t)bh * S_ + qg0 + r];
    }

    const __bf16* kgbase = Kh + (size_t)(b * S_ + srow) * D_ + h * HD_ + sc8;
    const __bf16* vgbase = Vt + (size_t)(b * D_ + h * HD_ + srow) * S_ + sc8;
    // prologue
    v8bf rk = *(const v8bf*)(kgbase);
    v8bf rv = *(const v8bf*)(vgbase);
    *(v8bf*)&sK[0][srow][sc8] = rk;
    *(v8bf*)&sV[0][srow][sc8] = rv;
    rk = *(const v8bf*)(kgbase + (size_t)64 * D_);
    rv = *(const v8bf*)(vgbase + 64);
    __syncthreads();

    v4f acc2[4] = {};
    int cur = 0;
    for (int kc = 0; kc < 32; kc++) {
        const int k0 = kc * 64;
        v4f acc[4] = {};
#pragma unroll
        for (int ct = 0; ct < 4; ct++) {
#pragma unroll
            for (int ks = 0; ks < 2; ks++) {
                v8bf kb = *(const v8bf*)&sK[cur][ct * 16 + fr][ks * 32 + fo];
                acc[ct] = mfma16(qa_h[ks], kb, acc[ct]);
                acc[ct] = mfma16(qa_l[ks], kb, acc[ct]);
            }
        }
        const bool band = (kc >= 2 * qt - 3) && (kc <= 2 * qt + 3);
        const bool left = kc < 2 * qt;
#pragma unroll
        for (int r = 0; r < 4; r++) {
            const int qg = qg0 + r;
#pragma unroll
            for (int ct = 0; ct < 4; ct++) {
                const int k = k0 + ct * 16 + fr;
                float bias;
                if (band) {
                    const int dd = k - qg;
                    const int j = dd < -128 ? 0 : (dd > 128 ? 256 : dd + 128);
                    bias = Rg[rbase0 + (size_t)r * RSTRIDE_ + j];
                } else {
                    bias = left ? rcL[r] : rcR[r];
                }
                float sv = acc[ct][r] * 0.125f + bias;
                if (!flr[r] && mask[mbase0 + (size_t)r * S_ + k] == 0) sv = -1e9f;
                const float p = __expf(sv - mfin[r]) * lfin[r];
                attn[abase0 + (size_t)r * S_ + k] = p;
                sP[myrow + r][ct * 16 + fr] = (__bf16)p;
            }
        }
        __syncthreads(); // sP visible
#pragma unroll
        for (int ks = 0; ks < 2; ks++) {
            v8bf pa = *(const v8bf*)&sP[w * 16 + fr][ks * 32 + fo];
#pragma unroll
            for (int ct = 0; ct < 4; ct++) {
                v8bf vb = *(const v8bf*)&sV[cur][ct * 16 + fr][ks * 32 + fo];
                acc2[ct] = mfma16(pa, vb, acc2[ct]);
            }
        }
        if (kc < 31) {
            *(v8bf*)&sK[cur ^ 1][srow][sc8] = rk;
            *(v8bf*)&sV[cur ^ 1][srow][sc8] = rv;
        }
        if (kc < 30) {
            rk = *(const v8bf*)(kgbase + (size_t)(k0 + 128) * D_);
            rv = *(const v8bf*)(vgbase + k0 + 128);
        }
        __syncthreads(); // next buffers visible; sP reads done
        cur ^= 1;
    }

#pragma unroll
    for (int ct = 0; ct < 4; ct++) {
#pragma unroll
        for (int r = 0; r < 4; r++) {
            const int qg = qg0 + r;
            const int d = ct * 16 + fr;
            ctx[(size_t)(b * S_ + qg) * D_ + h * HD_ + d] = (__bf16)acc2[ct][r];
        }
    }
}

// ---------------------------------------------------------------------------
// Output projection: out = ctx @ wo^T + bias (plain bf16 MFMA, fp32 out)
// ---------------------------------------------------------------------------
__global__ __launch_bounds__(256) void k_outproj(const __bf16* __restrict__ A,
                                                 const __bf16* __restrict__ Bw,
                                                 const float* __restrict__ bias,
                                                 float* __restrict__ out) {
    __shared__ __bf16 sA[64][72], sB[64][72];
    const int n0 = blockIdx.x * 64;
    const int m0 = blockIdx.y * 64;
    const int tid = threadIdx.x, lane = tid & 63, wid = tid >> 6;
    const int fr = lane & 15, fo = (lane >> 4) * 8;
    const int srow = tid >> 2, scol = (tid & 3) * 16;
    v4f acc[4] = {};
    for (int k0 = 0; k0 < D_; k0 += 64) {
        const size_t ga = (size_t)(m0 + srow) * D_ + k0 + scol;
        const size_t gb = (size_t)(n0 + srow) * D_ + k0 + scol;
        *(v8bf*)&sA[srow][scol]     = *(const v8bf*)(A + ga);
        *(v8bf*)&sA[srow][scol + 8] = *(const v8bf*)(A + ga + 8);
        *(v8bf*)&sB[srow][scol]     = *(const v8bf*)(Bw + gb);
        *(v8bf*)&sB[srow][scol + 8] = *(const v8bf*)(Bw + gb + 8);
        __syncthreads();
#pragma unroll
        for (int ks = 0; ks < 2; ks++) {
            v8bf a = *(const v8bf*)&sA[wid * 16 + fr][ks * 32 + fo];
#pragma unroll
            for (int nt = 0; nt < 4; nt++) {
                v8bf bb = *(const v8bf*)&sB[nt * 16 + fr][ks * 32 + fo];
                acc[nt] = mfma16(a, bb, acc[nt]);
            }
        }
        __syncthreads();
    }
#pragma unroll
    for (int nt = 0; nt < 4; nt++) {
        const float bv = bias[n0 + nt * 16 + fr];
#pragma unroll
        for (int r = 0; r < 4; r++) {
            const int row = m0 + wid * 16 + (lane >> 4) * 4 + r;
            out[(size_t)row * D_ + n0 + nt * 16 + fr] = acc[nt][r] + bv;
        }
    }
}

// ---------------------------------------------------------------------------
extern "C" void kernel_launch(void* const* d_in, const int* in_sizes, int n_in,
                              void* d_out, int out_size, void* d_ws, size_t ws_size,
                              hipStream_t stream) {
    (void)in_sizes; (void)n_in; (void)out_size; (void)ws_size;
    const float* x    = (const float*)d_in[0];
    const int*   mask = (const int*)d_in[1];
    const float* wq   = (const float*)d_in[2];
    const float* wk   = (const float*)d_in[3];
    const float* wv   = (const float*)d_in[4];
    const float* wo   = (const float*)d_in[5];
    const float* wob  = (const float*)d_in[6];
    const float* rel  = (const float*)d_in[7];
    float* out  = (float*)d_out;
    float* attn = out + (size_t)B_ * S_ * D_;

    char* p = (char*)d_ws;
    auto alloc = [&](size_t bytes) -> char* {
        char* r = p;
        p += (bytes + 255) & ~(size_t)255;
        return r;
    };
    const size_t BSD = (size_t)B_ * S_ * D_;
    const size_t DD  = (size_t)D_ * D_;
    __bf16* xh   = (__bf16*)alloc(BSD * 2);
    __bf16* xl   = (__bf16*)alloc(BSD * 2);
    __bf16* wqh  = (__bf16*)alloc(DD * 2);
    __bf16* wql  = (__bf16*)alloc(DD * 2);
    __bf16* wkh  = (__bf16*)alloc(DD * 2);
    __bf16* wkl  = (__bf16*)alloc(DD * 2);
    __bf16* wvh  = (__bf16*)alloc(DD * 2);
    __bf16* wvl  = (__bf16*)alloc(DD * 2);
    __bf16* woh  = (__bf16*)alloc(DD * 2);
    __bf16* wol  = (__bf16*)alloc(DD * 2);
    __bf16* relh = (__bf16*)alloc((size_t)NJ_ * HD_ * 2);
    __bf16* rell = (__bf16*)alloc((size_t)NJ_ * HD_ * 2);
    __bf16* Qh   = (__bf16*)alloc(BSD * 2);
    __bf16* Ql   = (__bf16*)alloc(BSD * 2);
    __bf16* Kh   = (__bf16*)alloc(BSD * 2);
    __bf16* Kl   = (__bf16*)alloc(BSD * 2);
    __bf16* Vb   = (__bf16*)alloc(BSD * 2);
    __bf16* Vt   = (__bf16*)alloc(BSD * 2);
    float*  Rg   = (float*)alloc((size_t)B_ * H_ * S_ * RSTRIDE_ * 4);
    float*  mrow = (float*)alloc((size_t)B_ * H_ * S_ * 4);
    float*  lrow = (float*)alloc((size_t)B_ * H_ * S_ * 4);
    __bf16* ctx  = (__bf16*)alloc(BSD * 2);
    unsigned char* flags = (unsigned char*)alloc((size_t)B_ * S_);

    // 1) splits
    k_split2<<<2048, 256, 0, stream>>>(x, xh, xl, (int)(BSD / 4));
    k_split2<<<1024, 256, 0, stream>>>(wq, wqh, wql, (int)(DD / 4));
    k_split2<<<1024, 256, 0, stream>>>(wk, wkh, wkl, (int)(DD / 4));
    k_split2<<<1024, 256, 0, stream>>>(wv, wvh, wvl, (int)(DD / 4));
    k_split2<<<1024, 256, 0, stream>>>(wo, woh, wol, (int)(DD / 4));
    k_split2<<<17, 256, 0, stream>>>(rel, relh, rell, (int)(NJ_ * HD_ / 4));

    // 2) mask row flags
    k_rowflag<<<B_ * S_, 256, 0, stream>>>(mask, flags);

    // 3) projections (Q,K split; V plain)
    k_proj<<<dim3(D_ / 64, B_ * S_ / 64), 256, 0, stream>>>(xh, xl, wqh, wql, Qh, Ql);
    k_proj<<<dim3(D_ / 64, B_ * S_ / 64), 256, 0, stream>>>(xh, xl, wkh, wkl, Kh, Kl);
    k_projV<<<dim3(D_ / 64, B_ * S_ / 64), 256, 0, stream>>>(xh, wvh, Vb);

    // 4) V transpose for PV B-operand
    k_vtrans<<<dim3(S_ / 64, D_ / 64, B_), 256, 0, stream>>>(Vb, Vt);

    // 5) rel bias table R
    k_relgemm<<<dim3(S_ / 64, B_ * H_), 256, 0, stream>>>(Qh, Ql, relh, rell, Rg);

    // 6) stats pass (m, l per row)
    k_stats<<<512, 512, 0, stream>>>(Qh, Ql, Kh, Rg, mask, flags, mrow, lrow);

    // 7) final pass (attn write + PV)
    k_final<<<512, 512, 0, stream>>>(Qh, Ql, Kh, Vt, Rg, mask, flags, mrow, lrow, attn, ctx);

    // 8) output projection
    k_outproj<<<dim3(D_ / 64, B_ * S_ / 64), 256, 0, stream>>>(ctx, woh, wob, out);
}